// Round 1
// baseline (156.288 us; speedup 1.0000x reference)
//
#include <hip/hip_runtime.h>
#include <hip/hip_bf16.h>
#include <stdint.h>

typedef __bf16 bf16;
typedef __bf16 bf16x8 __attribute__((ext_vector_type(8)));
typedef __bf16 bf16x4 __attribute__((ext_vector_type(4)));
typedef float f32x4 __attribute__((ext_vector_type(4)));

#define KDIM 768
#define NHEAD 12
#define HDIM 64
#define NTOK 1024
#define BATCH 8

// ---------------- fp32 -> bf16 convert ----------------
__global__ void k_cvt_bf16(const float* __restrict__ in, bf16* __restrict__ out, int n) {
    int i = (blockIdx.x * blockDim.x + threadIdx.x) * 4;
    if (i >= n) return;
    float4 v = *(const float4*)(in + i);
    bf16x4 o;
    o[0] = (bf16)v.x; o[1] = (bf16)v.y; o[2] = (bf16)v.z; o[3] = (bf16)v.w;
    *(bf16x4*)(out + i) = o;
}

// ---------------- QKV GEMM: [8192x768] x [2304x768]^T -> scatter q,k,v ----------------
// BM=BN=128, BK=32, 4 waves (2x2), each wave 64x64 (4x4 frags of 16x16x32 bf16 MFMA)
#define BM 128
#define BN 128
#define BK 32

__global__ __launch_bounds__(256) void k_gemm_qkv(
    const bf16* __restrict__ A,    // x_bf16 [8192][768]
    const bf16* __restrict__ W,    // w_qkv_bf16 [2304][768]
    bf16* __restrict__ qb, bf16* __restrict__ kb, bf16* __restrict__ vb)
{
    __shared__ bf16 As[BM * BK];
    __shared__ bf16 Bs[BN * BK];
    const int t = threadIdx.x;
    const int lane = t & 63;
    const int wv = t >> 6;
    const int wr = wv >> 1, wc = wv & 1;
    const int lr = lane & 15, lkb = (lane >> 4) * 8;
    const int bm = blockIdx.x, bn = blockIdx.y;

    const bf16* Ab = A + (size_t)bm * BM * KDIM;
    const bf16* Wb = W + (size_t)bn * BN * KDIM;

    const int srow = t >> 2;           // 0..63
    const int scol = (t & 3) * 8;      // 0,8,16,24

    f32x4 acc[4][4] = {};

    for (int k0 = 0; k0 < KDIM; k0 += BK) {
        bf16x8 a0 = *(const bf16x8*)(Ab + (size_t)srow * KDIM + k0 + scol);
        bf16x8 a1 = *(const bf16x8*)(Ab + (size_t)(srow + 64) * KDIM + k0 + scol);
        bf16x8 b0 = *(const bf16x8*)(Wb + (size_t)srow * KDIM + k0 + scol);
        bf16x8 b1 = *(const bf16x8*)(Wb + (size_t)(srow + 64) * KDIM + k0 + scol);
        __syncthreads();   // previous iteration's frag reads complete
        *(bf16x8*)&As[srow * BK + scol] = a0;
        *(bf16x8*)&As[(srow + 64) * BK + scol] = a1;
        *(bf16x8*)&Bs[srow * BK + scol] = b0;
        *(bf16x8*)&Bs[(srow + 64) * BK + scol] = b1;
        __syncthreads();
        bf16x8 af[4], bfr[4];
#pragma unroll
        for (int m = 0; m < 4; ++m)
            af[m] = *(const bf16x8*)&As[(wr * 64 + m * 16 + lr) * BK + lkb];
#pragma unroll
        for (int n = 0; n < 4; ++n)
            bfr[n] = *(const bf16x8*)&Bs[(wc * 64 + n * 16 + lr) * BK + lkb];
#pragma unroll
        for (int m = 0; m < 4; ++m)
#pragma unroll
            for (int n = 0; n < 4; ++n)
                acc[m][n] = __builtin_amdgcn_mfma_f32_16x16x32_bf16(af[m], bfr[n], acc[m][n], 0, 0, 0);
    }

    // epilogue: C[row][col], col = lane&15, row = (lane>>4)*4 + reg  [measured m89]
    // o = global col in [0,2304): s=o/768, head=(o%768)/64, d=o%64
    const float QSC = 0.18033688011112042f;  // 0.125 * log2(e) folded into q
#pragma unroll
    for (int n = 0; n < 4; ++n) {
        int o = bn * BN + wc * 64 + n * 16 + lr;
        int s = o / 768;
        int rem = o - s * 768;
        int head = rem >> 6;
        int d = o & 63;
        bf16* dst = (s == 0) ? qb : ((s == 1) ? kb : vb);
        float sc = (s == 0) ? QSC : 1.0f;
#pragma unroll
        for (int m = 0; m < 4; ++m) {
            int grow = bm * BM + wr * 64 + m * 16 + (lane >> 4) * 4;
            int bidx = grow >> 10;
            int tok = grow & 1023;
            size_t base = (((size_t)bidx * NHEAD + head) * NTOK + tok) * HDIM + d;
#pragma unroll
            for (int r = 0; r < 4; ++r)
                dst[base + (size_t)r * HDIM] = (bf16)(acc[m][n][r] * sc);
        }
    }
}

// ---------------- Proj GEMM: [8192x768] x [768x768]^T + bias -> fp32 out ----------------
__global__ __launch_bounds__(256) void k_gemm_proj(
    const bf16* __restrict__ A,    // attn_out bf16 [8192][768]
    const bf16* __restrict__ W,    // w_proj bf16 [768][768]
    const float* __restrict__ bias,
    float* __restrict__ out)
{
    __shared__ bf16 As[BM * BK];
    __shared__ bf16 Bs[BN * BK];
    const int t = threadIdx.x;
    const int lane = t & 63;
    const int wv = t >> 6;
    const int wr = wv >> 1, wc = wv & 1;
    const int lr = lane & 15, lkb = (lane >> 4) * 8;
    const int bm = blockIdx.x, bn = blockIdx.y;

    const bf16* Ab = A + (size_t)bm * BM * KDIM;
    const bf16* Wb = W + (size_t)bn * BN * KDIM;

    const int srow = t >> 2;
    const int scol = (t & 3) * 8;

    f32x4 acc[4][4] = {};

    for (int k0 = 0; k0 < KDIM; k0 += BK) {
        bf16x8 a0 = *(const bf16x8*)(Ab + (size_t)srow * KDIM + k0 + scol);
        bf16x8 a1 = *(const bf16x8*)(Ab + (size_t)(srow + 64) * KDIM + k0 + scol);
        bf16x8 b0 = *(const bf16x8*)(Wb + (size_t)srow * KDIM + k0 + scol);
        bf16x8 b1 = *(const bf16x8*)(Wb + (size_t)(srow + 64) * KDIM + k0 + scol);
        __syncthreads();
        *(bf16x8*)&As[srow * BK + scol] = a0;
        *(bf16x8*)&As[(srow + 64) * BK + scol] = a1;
        *(bf16x8*)&Bs[srow * BK + scol] = b0;
        *(bf16x8*)&Bs[(srow + 64) * BK + scol] = b1;
        __syncthreads();
        bf16x8 af[4], bfr[4];
#pragma unroll
        for (int m = 0; m < 4; ++m)
            af[m] = *(const bf16x8*)&As[(wr * 64 + m * 16 + lr) * BK + lkb];
#pragma unroll
        for (int n = 0; n < 4; ++n)
            bfr[n] = *(const bf16x8*)&Bs[(wc * 64 + n * 16 + lr) * BK + lkb];
#pragma unroll
        for (int m = 0; m < 4; ++m)
#pragma unroll
            for (int n = 0; n < 4; ++n)
                acc[m][n] = __builtin_amdgcn_mfma_f32_16x16x32_bf16(af[m], bfr[n], acc[m][n], 0, 0, 0);
    }

#pragma unroll
    for (int n = 0; n < 4; ++n) {
        int col = bn * BN + wc * 64 + n * 16 + lr;
        float bv = bias[col];
#pragma unroll
        for (int m = 0; m < 4; ++m) {
            int grow = bm * BM + wr * 64 + m * 16 + (lane >> 4) * 4;
#pragma unroll
            for (int r = 0; r < 4; ++r)
                out[(size_t)(grow + r) * KDIM + col] = acc[m][n][r] + bv;
        }
    }
}

// ---------------- banded flash attention ----------------
// grid (16, 96): x = q-block (== h_q since each 64-token block is one grid row), y = b*12+h
// 4 waves x 16 q-rows. Visible keys: h_k in [h_q-3,h_q+3], |w_q-w_k|<=5 (analytic mask).
__global__ __launch_bounds__(256) void k_attn(
    const bf16* __restrict__ qbuf, const bf16* __restrict__ kbuf,
    const bf16* __restrict__ vbuf, bf16* __restrict__ ob)
{
    const int qblk = blockIdx.x;     // 0..15 == h_q
    const int bh = blockIdx.y;       // 0..95
    const int head = bh % NHEAD, bidx = bh / NHEAD;
    const bf16* Q  = qbuf + (size_t)bh * NTOK * HDIM;
    const bf16* Kp = kbuf + (size_t)bh * NTOK * HDIM;
    const bf16* Vp = vbuf + (size_t)bh * NTOK * HDIM;

    const int t = threadIdx.x, lane = t & 63, wv = t >> 6;
    const int lr = lane & 15, lg = lane >> 4, lkb = lg * 8;

    __shared__ bf16 vT[64 * 64];         // transposed V row-block [d][j], XOR-swizzled
    __shared__ bf16 pls[4][16 * 32];     // per-wave P tile, XOR-swizzled

    // Q fragments (A operand): row = lane&15, k-chunk = (lane>>4)*8
    bf16x8 qf[2];
#pragma unroll
    for (int ks = 0; ks < 2; ++ks)
        qf[ks] = *(const bf16x8*)(Q + (size_t)(qblk * 64 + wv * 16 + lr) * HDIM + ks * 32 + lkb);

    f32x4 acc[4] = {};
    float mrow[4] = {-1e30f, -1e30f, -1e30f, -1e30f};
    float lrow[4] = {0.f, 0.f, 0.f, 0.f};

    const int kh0 = (qblk - 3 < 0) ? 0 : qblk - 3;
    const int kh1 = (qblk + 3 > 15) ? 15 : qblk + 3;

    const int vj  = t >> 2;          // key within row-block: 0..63
    const int vd0 = (t & 3) * 16;    // d chunk

    for (int kh = kh0; kh <= kh1; ++kh) {
        // ---- stage V^T (64 keys x 64 d -> vT[d][j], swizzle byte ^= (d&7)<<4) ----
        {
            const bf16* src = Vp + (size_t)(kh * 64 + vj) * HDIM + vd0;
            bf16x8 v0 = *(const bf16x8*)(src);
            bf16x8 v1 = *(const bf16x8*)(src + 8);
            __syncthreads();  // all waves done reading previous vT
            char* vb8 = (char*)vT;
#pragma unroll
            for (int ii = 0; ii < 8; ++ii) {
                int d = vd0 + ii;
                int bo = (d << 7) + (vj << 1);
                *(bf16*)(vb8 + (bo ^ ((d & 7) << 4))) = v0[ii];
            }
#pragma unroll
            for (int ii = 0; ii < 8; ++ii) {
                int d = vd0 + 8 + ii;
                int bo = (d << 7) + (vj << 1);
                *(bf16*)(vb8 + (bo ^ ((d & 7) << 4))) = v1[ii];
            }
        }
        __syncthreads();

#pragma unroll
        for (int kt = 0; kt < 2; ++kt) {
            // ---- S = Q K^T (16 q-rows x 32 keys), logits already in log2 domain ----
            f32x4 s[2] = {};
#pragma unroll
            for (int n = 0; n < 2; ++n)
#pragma unroll
                for (int ks = 0; ks < 2; ++ks) {
                    bf16x8 kf = *(const bf16x8*)(Kp + (size_t)(kh * 64 + kt * 32 + n * 16 + lr) * HDIM + ks * 32 + lkb);
                    s[n] = __builtin_amdgcn_mfma_f32_16x16x32_bf16(qf[ks], kf, s[n], 0, 0, 0);
                }
            // ---- analytic mask: |w_q - w_k| <= 5 ----
            const int wq0 = wv * 16 + lg * 4;
#pragma unroll
            for (int n = 0; n < 2; ++n) {
                int wk = kt * 32 + n * 16 + lr;
#pragma unroll
                for (int r = 0; r < 4; ++r) {
                    int dw = wq0 + r - wk;
                    if (dw < -5 || dw > 5) s[n][r] = -1e30f;
                }
            }
            // ---- online softmax (rows live on 16-lane groups) ----
            float pm[4];
#pragma unroll
            for (int r = 0; r < 4; ++r) pm[r] = fmaxf(s[0][r], s[1][r]);
#pragma unroll
            for (int off = 1; off < 16; off <<= 1)
#pragma unroll
                for (int r = 0; r < 4; ++r) pm[r] = fmaxf(pm[r], __shfl_xor(pm[r], off));
            float scl[4];
#pragma unroll
            for (int r = 0; r < 4; ++r) {
                float mn = fmaxf(mrow[r], pm[r]);
                scl[r] = exp2f(mrow[r] - mn);
                mrow[r] = mn;
            }
#pragma unroll
            for (int dt = 0; dt < 4; ++dt)
#pragma unroll
                for (int r = 0; r < 4; ++r) acc[dt][r] *= scl[r];
            // P tile -> LDS (C/D layout -> A-frag layout), swizzle byte ^= (row&3)<<4
            char* pb8 = (char*)pls[wv];
#pragma unroll
            for (int r = 0; r < 4; ++r) {
                float p0 = exp2f(s[0][r] - mrow[r]);
                float p1 = exp2f(s[1][r] - mrow[r]);
                lrow[r] = lrow[r] * scl[r] + p0 + p1;
                int row = lg * 4 + r;
                int bo0 = row * 64 + (0 * 16 + lr) * 2;
                int bo1 = row * 64 + (1 * 16 + lr) * 2;
                *(bf16*)(pb8 + (bo0 ^ ((r & 3) << 4))) = (bf16)p0;
                *(bf16*)(pb8 + (bo1 ^ ((r & 3) << 4))) = (bf16)p1;
            }
            // ---- PV: A = P[16x32] (from pls), B = V[32 keys x 64 d] (from vT) ----
            bf16x8 pf = *(const bf16x8*)(pb8 + ((lr * 64 + lg * 16) ^ ((lr & 3) << 4)));
#pragma unroll
            for (int dt = 0; dt < 4; ++dt) {
                int row = dt * 16 + lr;
                bf16x8 vf = *(const bf16x8*)((char*)vT + (((row << 7) + kt * 64 + lg * 16) ^ ((row & 7) << 4)));
                acc[dt] = __builtin_amdgcn_mfma_f32_16x16x32_bf16(pf, vf, acc[dt], 0, 0, 0);
            }
        } // kt
    } // kh

    // ---- finalize: row-sum of l across 16-lane group, divide, write [b,n,h*64+d] bf16 ----
#pragma unroll
    for (int off = 1; off < 16; off <<= 1)
#pragma unroll
        for (int r = 0; r < 4; ++r) lrow[r] += __shfl_xor(lrow[r], off);

#pragma unroll
    for (int r = 0; r < 4; ++r) {
        float inv = 1.0f / lrow[r];
        int tok = qblk * 64 + wv * 16 + lg * 4 + r;
        size_t rowbase = ((size_t)bidx * NTOK + tok) * KDIM + head * HDIM;
#pragma unroll
        for (int dt = 0; dt < 4; ++dt)
            ob[rowbase + dt * 16 + lr] = (bf16)(acc[dt][r] * inv);
    }
}

// ---------------- launcher ----------------
extern "C" void kernel_launch(void* const* d_in, const int* in_sizes, int n_in,
                              void* d_out, int out_size, void* d_ws, size_t ws_size,
                              hipStream_t stream) {
    const float* x      = (const float*)d_in[0];
    const float* w_qkv  = (const float*)d_in[1];
    const float* w_proj = (const float*)d_in[2];
    const float* b_proj = (const float*)d_in[3];
    // d_in[4] = mask: recomputed analytically in-kernel
    float* out = (float*)d_out;

    char* ws = (char*)d_ws;
    bf16* xb  = (bf16*)(ws);                  // 8192*768*2   = 12582912
    bf16* wqb = (bf16*)(ws + 12582912);       // 2304*768*2   =  3538944
    bf16* wpb = (bf16*)(ws + 16121856);       // 768*768*2    =  1179648
    bf16* qb  = (bf16*)(ws + 17301504);       // 96*1024*64*2 = 12582912
    bf16* kb  = (bf16*)(ws + 29884416);
    bf16* vb  = (bf16*)(ws + 42467328);
    bf16* aob = (bf16*)(ws + 55050240);       // attn out bf16 [8192][768]

    hipLaunchKernelGGL(k_cvt_bf16, dim3(6144), dim3(256), 0, stream, x, xb, 6291456);
    hipLaunchKernelGGL(k_cvt_bf16, dim3(1728), dim3(256), 0, stream, w_qkv, wqb, 1769472);
    hipLaunchKernelGGL(k_cvt_bf16, dim3(576),  dim3(256), 0, stream, w_proj, wpb, 589824);
    hipLaunchKernelGGL(k_gemm_qkv, dim3(64, 18), dim3(256), 0, stream, xb, wqb, qb, kb, vb);
    hipLaunchKernelGGL(k_attn,     dim3(16, 96), dim3(256), 0, stream, qb, kb, vb, aob);
    hipLaunchKernelGGL(k_gemm_proj, dim3(64, 6), dim3(256), 0, stream, aob, wpb, b_proj, out);
}

// Round 2
// 116.986 us; speedup vs baseline: 1.3360x; 1.3360x over previous
//
#include <hip/hip_runtime.h>
#include <hip/hip_bf16.h>
#include <stdint.h>

typedef __bf16 bf16;
typedef __bf16 bf16x8 __attribute__((ext_vector_type(8)));
typedef __bf16 bf16x4 __attribute__((ext_vector_type(4)));
typedef float f32x4 __attribute__((ext_vector_type(4)));

#define KDIM 768
#define NHEAD 12
#define HDIM 64
#define NTOK 1024
#define BATCH 8

// XOR swizzle for row-major [row][128B-row] LDS tiles: 16B chunk -> distinct bank-quad
#define SWZ(row, b) ((b) ^ (((row) & 7) << 4))

__device__ __forceinline__ void gl_lds16(const bf16* g, bf16* l) {
    __builtin_amdgcn_global_load_lds((const __attribute__((address_space(1))) void*)g,
                                     (__attribute__((address_space(3))) void*)l, 16, 0, 0);
}

// ---------------- fp32 -> bf16 convert ----------------
__global__ void k_cvt_bf16(const float* __restrict__ in, bf16* __restrict__ out, int n) {
    int i = (blockIdx.x * blockDim.x + threadIdx.x) * 4;
    if (i >= n) return;
    float4 v = *(const float4*)(in + i);
    bf16x4 o;
    o[0] = (bf16)v.x; o[1] = (bf16)v.y; o[2] = (bf16)v.z; o[3] = (bf16)v.w;
    *(bf16x4*)(out + i) = o;
}

// ---------------- QKV GEMM: [8192x768] x [2304x768]^T -> scatter q,k,v ----------------
#define BM 128
#define BN 128
#define BK 32

__global__ __launch_bounds__(256) void k_gemm_qkv(
    const bf16* __restrict__ A, const bf16* __restrict__ W,
    bf16* __restrict__ qb, bf16* __restrict__ kb, bf16* __restrict__ vb)
{
    __shared__ bf16 As[BM * BK];
    __shared__ bf16 Bs[BN * BK];
    const int t = threadIdx.x;
    const int lane = t & 63;
    const int wv = t >> 6;
    const int wr = wv >> 1, wc = wv & 1;
    const int lr = lane & 15, lkb = (lane >> 4) * 8;
    const int bm = blockIdx.x, bn = blockIdx.y;

    const bf16* Ab = A + (size_t)bm * BM * KDIM;
    const bf16* Wb = W + (size_t)bn * BN * KDIM;

    const int srow = t >> 2;           // 0..63  (= wv*16 + (lane>>2))
    const int scol = (t & 3) * 8;      // 0,8,16,24

    f32x4 acc[4][4] = {};

    for (int k0 = 0; k0 < KDIM; k0 += BK) {
        __syncthreads();   // previous iteration's frag reads complete
        gl_lds16(Ab + (size_t)srow * KDIM + k0 + scol,        As + wv * 512);
        gl_lds16(Ab + (size_t)(srow + 64) * KDIM + k0 + scol, As + 2048 + wv * 512);
        gl_lds16(Wb + (size_t)srow * KDIM + k0 + scol,        Bs + wv * 512);
        gl_lds16(Wb + (size_t)(srow + 64) * KDIM + k0 + scol, Bs + 2048 + wv * 512);
        __syncthreads();
        bf16x8 af[4], bfr[4];
#pragma unroll
        for (int m = 0; m < 4; ++m)
            af[m] = *(const bf16x8*)&As[(wr * 64 + m * 16 + lr) * BK + lkb];
#pragma unroll
        for (int n = 0; n < 4; ++n)
            bfr[n] = *(const bf16x8*)&Bs[(wc * 64 + n * 16 + lr) * BK + lkb];
#pragma unroll
        for (int m = 0; m < 4; ++m)
#pragma unroll
            for (int n = 0; n < 4; ++n)
                acc[m][n] = __builtin_amdgcn_mfma_f32_16x16x32_bf16(af[m], bfr[n], acc[m][n], 0, 0, 0);
    }

    const float QSC = 0.18033688011112042f;  // 0.125 * log2(e) folded into q
#pragma unroll
    for (int n = 0; n < 4; ++n) {
        int o = bn * BN + wc * 64 + n * 16 + lr;
        int s = o / 768;
        int rem = o - s * 768;
        int head = rem >> 6;
        int d = o & 63;
        bf16* dst = (s == 0) ? qb : ((s == 1) ? kb : vb);
        float sc = (s == 0) ? QSC : 1.0f;
#pragma unroll
        for (int m = 0; m < 4; ++m) {
            int grow = bm * BM + wr * 64 + m * 16 + (lane >> 4) * 4;
            int bidx = grow >> 10;
            int tok = grow & 1023;
            size_t base = (((size_t)bidx * NHEAD + head) * NTOK + tok) * HDIM + d;
#pragma unroll
            for (int r = 0; r < 4; ++r)
                dst[base + (size_t)r * HDIM] = (bf16)(acc[m][n][r] * sc);
        }
    }
}

// ---------------- Proj GEMM: [8192x768] x [768x768]^T + bias -> fp32 out ----------------
__global__ __launch_bounds__(256) void k_gemm_proj(
    const bf16* __restrict__ A, const bf16* __restrict__ W,
    const float* __restrict__ bias, float* __restrict__ out)
{
    __shared__ bf16 As[BM * BK];
    __shared__ bf16 Bs[BN * BK];
    const int t = threadIdx.x;
    const int lane = t & 63;
    const int wv = t >> 6;
    const int wr = wv >> 1, wc = wv & 1;
    const int lr = lane & 15, lkb = (lane >> 4) * 8;
    const int bm = blockIdx.x, bn = blockIdx.y;

    const bf16* Ab = A + (size_t)bm * BM * KDIM;
    const bf16* Wb = W + (size_t)bn * BN * KDIM;

    const int srow = t >> 2;
    const int scol = (t & 3) * 8;

    f32x4 acc[4][4] = {};

    for (int k0 = 0; k0 < KDIM; k0 += BK) {
        __syncthreads();
        gl_lds16(Ab + (size_t)srow * KDIM + k0 + scol,        As + wv * 512);
        gl_lds16(Ab + (size_t)(srow + 64) * KDIM + k0 + scol, As + 2048 + wv * 512);
        gl_lds16(Wb + (size_t)srow * KDIM + k0 + scol,        Bs + wv * 512);
        gl_lds16(Wb + (size_t)(srow + 64) * KDIM + k0 + scol, Bs + 2048 + wv * 512);
        __syncthreads();
        bf16x8 af[4], bfr[4];
#pragma unroll
        for (int m = 0; m < 4; ++m)
            af[m] = *(const bf16x8*)&As[(wr * 64 + m * 16 + lr) * BK + lkb];
#pragma unroll
        for (int n = 0; n < 4; ++n)
            bfr[n] = *(const bf16x8*)&Bs[(wc * 64 + n * 16 + lr) * BK + lkb];
#pragma unroll
        for (int m = 0; m < 4; ++m)
#pragma unroll
            for (int n = 0; n < 4; ++n)
                acc[m][n] = __builtin_amdgcn_mfma_f32_16x16x32_bf16(af[m], bfr[n], acc[m][n], 0, 0, 0);
    }

#pragma unroll
    for (int n = 0; n < 4; ++n) {
        int col = bn * BN + wc * 64 + n * 16 + lr;
        float bv = bias[col];
#pragma unroll
        for (int m = 0; m < 4; ++m) {
            int grow = bm * BM + wr * 64 + m * 16 + (lane >> 4) * 4;
#pragma unroll
            for (int r = 0; r < 4; ++r)
                out[(size_t)(grow + r) * KDIM + col] = acc[m][n][r] + bv;
        }
    }
}

// ---------------- banded flash attention ----------------
// grid: 1536 linear blocks, XCD-swizzled: xcd=x&7 owns 12 consecutive bh (K/V L2-resident).
// 4 waves x 16 q-rows (wave wv's queries have w in [16wv,16wv+16) -> visible key tiles
// j in {wv-1,wv,wv+1} only). K and V^T staged in LDS (XOR-swizzled); next kh's K/V
// reg-prefetched across raw s_barrier (no vmcnt drain).
__global__ __launch_bounds__(256) void k_attn(
    const bf16* __restrict__ qbuf, const bf16* __restrict__ kbuf,
    const bf16* __restrict__ vbuf, bf16* __restrict__ ob)
{
    const int x = blockIdx.x;
    const int sub = x >> 3;
    const int bh = (x & 7) * 12 + (sub >> 4);   // 12 bh per XCD
    const int qblk = sub & 15;                   // == h_q
    const int head = bh % NHEAD, bidx = bh / NHEAD;
    const bf16* Q  = qbuf + (size_t)bh * NTOK * HDIM;
    const bf16* Kp = kbuf + (size_t)bh * NTOK * HDIM;
    const bf16* Vp = vbuf + (size_t)bh * NTOK * HDIM;

    const int t = threadIdx.x, lane = t & 63, wv = t >> 6;
    const int lr = lane & 15, lg = lane >> 4, lkb = lg * 8;

    __shared__ bf16 Ks[64 * 64];      // [key][d], swizzled
    __shared__ bf16 vT[64 * 64];      // [d][key], swizzled
    __shared__ bf16 pls[4][16 * 64];  // per-wave P [q][key], swizzled

    // zero own wave's P tile once (invisible key tiles are never written; set is constant)
    {
        bf16x8 z = {};
        *(bf16x8*)&pls[wv][lane * 16] = z;
        *(bf16x8*)&pls[wv][lane * 16 + 8] = z;
    }

    // Q fragments (A operand): row = lane&15, k-chunk = (lane>>4)*8
    bf16x8 qf[2];
#pragma unroll
    for (int ks = 0; ks < 2; ++ks)
        qf[ks] = *(const bf16x8*)(Q + (size_t)(qblk * 64 + wv * 16 + lr) * HDIM + ks * 32 + lkb);

    f32x4 acc[4] = {};
    float mrow[4] = {-1e30f, -1e30f, -1e30f, -1e30f};
    float lrow[4] = {0.f, 0.f, 0.f, 0.f};

    const int kh0 = (qblk - 3 < 0) ? 0 : qblk - 3;
    const int kh1 = (qblk + 3 > 15) ? 15 : qblk + 3;

    const int sj = t >> 2;           // staged key 0..63
    const int sd = (t & 3) * 16;     // staged d elt 0,16,32,48

    // prologue: load kh0's K/V into regs
    const bf16* ks0 = Kp + (size_t)(kh0 * 64 + sj) * HDIM + sd;
    const bf16* vs0 = Vp + (size_t)(kh0 * 64 + sj) * HDIM + sd;
    bf16x8 gk0 = *(const bf16x8*)ks0, gk1 = *(const bf16x8*)(ks0 + 8);
    bf16x8 gv0 = *(const bf16x8*)vs0, gv1 = *(const bf16x8*)(vs0 + 8);

    char* kb8 = (char*)Ks;
    char* vb8 = (char*)vT;
    char* pb8 = (char*)pls[wv];
    const int wq0 = wv * 16 + lg * 4;

    for (int kh = kh0; kh <= kh1; ++kh) {
        // all waves done reading LDS from previous iteration
        asm volatile("s_waitcnt lgkmcnt(0)" ::: "memory");
        __builtin_amdgcn_s_barrier();
        // stage K (row-major, swizzled)
        {
            int kbo = sj * 128 + sd * 2;
            *(bf16x8*)(kb8 + SWZ(sj, kbo)) = gk0;
            *(bf16x8*)(kb8 + SWZ(sj, kbo + 16)) = gk1;
        }
        // stage V^T (scatter transpose, swizzled)
#pragma unroll
        for (int ii = 0; ii < 8; ++ii) {
            int d = sd + ii;
            *(bf16*)(vb8 + SWZ(d, (d << 7) + (sj << 1))) = gv0[ii];
        }
#pragma unroll
        for (int ii = 0; ii < 8; ++ii) {
            int d = sd + 8 + ii;
            *(bf16*)(vb8 + SWZ(d, (d << 7) + (sj << 1))) = gv1[ii];
        }
        // prefetch next kh's K/V (stays in flight across the raw barrier)
        if (kh < kh1) {
            const bf16* kn = Kp + (size_t)((kh + 1) * 64 + sj) * HDIM + sd;
            const bf16* vn = Vp + (size_t)((kh + 1) * 64 + sj) * HDIM + sd;
            gk0 = *(const bf16x8*)kn; gk1 = *(const bf16x8*)(kn + 8);
            gv0 = *(const bf16x8*)vn; gv1 = *(const bf16x8*)(vn + 8);
        }
        // my LDS writes complete -> barrier (NO vmcnt drain: prefetch overlaps compute)
        asm volatile("s_waitcnt lgkmcnt(0)" ::: "memory");
        __builtin_amdgcn_s_barrier();

        // ---- QK^T over visible key tiles (j in {wv-1,wv,wv+1} ∩ [0,3]) ----
        f32x4 s[3];
#pragma unroll
        for (int jj = 0; jj < 3; ++jj) {
            int j = wv - 1 + jj;
            if (j >= 0 && j <= 3) {        // wave-uniform
                int key = j * 16 + lr;
                int kbase = key * 128;
                bf16x8 kf0 = *(const bf16x8*)(kb8 + SWZ(key, kbase + lg * 16));
                bf16x8 kf1 = *(const bf16x8*)(kb8 + SWZ(key, kbase + 64 + lg * 16));
                f32x4 sv = {};
                sv = __builtin_amdgcn_mfma_f32_16x16x32_bf16(qf[0], kf0, sv, 0, 0, 0);
                sv = __builtin_amdgcn_mfma_f32_16x16x32_bf16(qf[1], kf1, sv, 0, 0, 0);
#pragma unroll
                for (int r = 0; r < 4; ++r) {
                    int dw = wq0 + r - key;
                    sv[r] = (dw >= -5 && dw <= 5) ? sv[r] : -1e30f;
                }
                s[jj] = sv;
            } else {
                s[jj] = f32x4{-1e30f, -1e30f, -1e30f, -1e30f};
            }
        }

        // ---- online softmax, once per kh (rows on 16-lane groups) ----
        float pm[4], scl[4];
#pragma unroll
        for (int r = 0; r < 4; ++r) pm[r] = fmaxf(fmaxf(s[0][r], s[1][r]), s[2][r]);
#pragma unroll
        for (int off = 1; off < 16; off <<= 1)
#pragma unroll
            for (int r = 0; r < 4; ++r) pm[r] = fmaxf(pm[r], __shfl_xor(pm[r], off));
#pragma unroll
        for (int r = 0; r < 4; ++r) {
            float mn = fmaxf(mrow[r], pm[r]);
            scl[r] = exp2f(mrow[r] - mn);
            mrow[r] = mn;
        }
#pragma unroll
        for (int dt = 0; dt < 4; ++dt)
#pragma unroll
            for (int r = 0; r < 4; ++r) acc[dt][r] *= scl[r];

        // ---- P = exp2(s - m) -> bf16 -> per-wave LDS tile ----
        float psum[4] = {0.f, 0.f, 0.f, 0.f};
#pragma unroll
        for (int jj = 0; jj < 3; ++jj) {
            int j = wv - 1 + jj;
            if (j >= 0 && j <= 3) {
#pragma unroll
                for (int r = 0; r < 4; ++r) {
                    float p = exp2f(s[jj][r] - mrow[r]);
                    psum[r] += p;
                    int row = lg * 4 + r;
                    *(bf16*)(pb8 + SWZ(row, row * 128 + (j * 16 + lr) * 2)) = (bf16)p;
                }
            }
        }
#pragma unroll
        for (int r = 0; r < 4; ++r) lrow[r] = lrow[r] * scl[r] + psum[r];

        // ---- PV: A = P[16x64] (2 K=32 chunks), B = V^T ----
        bf16x8 pf0 = *(const bf16x8*)(pb8 + SWZ(lr, lr * 128 + lg * 16));
        bf16x8 pf1 = *(const bf16x8*)(pb8 + SWZ(lr, lr * 128 + 64 + lg * 16));
#pragma unroll
        for (int dt = 0; dt < 4; ++dt) {
            int vrow = dt * 16 + lr;
            bf16x8 vf0 = *(const bf16x8*)(vb8 + SWZ(vrow, vrow * 128 + lg * 16));
            bf16x8 vf1 = *(const bf16x8*)(vb8 + SWZ(vrow, vrow * 128 + 64 + lg * 16));
            acc[dt] = __builtin_amdgcn_mfma_f32_16x16x32_bf16(pf0, vf0, acc[dt], 0, 0, 0);
            acc[dt] = __builtin_amdgcn_mfma_f32_16x16x32_bf16(pf1, vf1, acc[dt], 0, 0, 0);
        }
    } // kh

    // ---- finalize ----
#pragma unroll
    for (int off = 1; off < 16; off <<= 1)
#pragma unroll
        for (int r = 0; r < 4; ++r) lrow[r] += __shfl_xor(lrow[r], off);

#pragma unroll
    for (int r = 0; r < 4; ++r) {
        float inv = 1.0f / lrow[r];
        int tok = qblk * 64 + wv * 16 + lg * 4 + r;
        size_t rowbase = ((size_t)bidx * NTOK + tok) * KDIM + head * HDIM;
#pragma unroll
        for (int dt = 0; dt < 4; ++dt)
            ob[rowbase + dt * 16 + lr] = (bf16)(acc[dt][r] * inv);
    }
}

// ---------------- launcher ----------------
extern "C" void kernel_launch(void* const* d_in, const int* in_sizes, int n_in,
                              void* d_out, int out_size, void* d_ws, size_t ws_size,
                              hipStream_t stream) {
    const float* x      = (const float*)d_in[0];
    const float* w_qkv  = (const float*)d_in[1];
    const float* w_proj = (const float*)d_in[2];
    const float* b_proj = (const float*)d_in[3];
    float* out = (float*)d_out;

    char* ws = (char*)d_ws;
    bf16* xb  = (bf16*)(ws);                  // 8192*768*2   = 12582912
    bf16* wqb = (bf16*)(ws + 12582912);       // 2304*768*2   =  3538944
    bf16* wpb = (bf16*)(ws + 16121856);       // 768*768*2    =  1179648
    bf16* qb  = (bf16*)(ws + 17301504);       // 96*1024*64*2 = 12582912
    bf16* kb  = (bf16*)(ws + 29884416);
    bf16* vb  = (bf16*)(ws + 42467328);
    bf16* aob = (bf16*)(ws + 55050240);       // attn out bf16 [8192][768]

    hipLaunchKernelGGL(k_cvt_bf16, dim3(6144), dim3(256), 0, stream, x, xb, 6291456);
    hipLaunchKernelGGL(k_cvt_bf16, dim3(1728), dim3(256), 0, stream, w_qkv, wqb, 1769472);
    hipLaunchKernelGGL(k_cvt_bf16, dim3(576),  dim3(256), 0, stream, w_proj, wpb, 589824);
    hipLaunchKernelGGL(k_gemm_qkv, dim3(64, 18), dim3(256), 0, stream, xb, wqb, qb, kb, vb);
    hipLaunchKernelGGL(k_attn,     dim3(1536), dim3(256), 0, stream, qb, kb, vb, aob);
    hipLaunchKernelGGL(k_gemm_proj, dim3(64, 6), dim3(256), 0, stream, aob, wpb, b_proj, out);
}

// Round 3
// 110.084 us; speedup vs baseline: 1.4197x; 1.0627x over previous
//
#include <hip/hip_runtime.h>
#include <hip/hip_bf16.h>
#include <stdint.h>

typedef __bf16 bf16;
typedef __bf16 bf16x8 __attribute__((ext_vector_type(8)));
typedef __bf16 bf16x4 __attribute__((ext_vector_type(4)));
typedef float f32x4 __attribute__((ext_vector_type(4)));

#define KDIM 768
#define NHEAD 12
#define HDIM 64
#define NTOK 1024
#define BATCH 8

// XOR swizzle for row-major [row][128B-row] LDS tiles: 16B chunk -> distinct bank-quad
#define SWZ(row, b) ((b) ^ (((row) & 7) << 4))

__device__ __forceinline__ void gl_lds16(const bf16* g, bf16* l) {
    __builtin_amdgcn_global_load_lds((const __attribute__((address_space(1))) void*)g,
                                     (__attribute__((address_space(3))) void*)l, 16, 0, 0);
}

// ---------------- fp32 -> bf16 convert (all three tensors, one launch) ----------------
__global__ void k_cvt_all(const float* __restrict__ x, const float* __restrict__ wq,
                          const float* __restrict__ wp, bf16* __restrict__ xb,
                          bf16* __restrict__ wqb, bf16* __restrict__ wpb) {
    int b = blockIdx.x;
    const float* src;
    bf16* dst;
    int base;
    if (b < 6144)       { src = x;  dst = xb;  base = b; }
    else if (b < 7872)  { src = wq; dst = wqb; base = b - 6144; }
    else                { src = wp; dst = wpb; base = b - 7872; }
    int i = (base * 256 + threadIdx.x) * 4;
    float4 v = *(const float4*)(src + i);
    bf16x4 o;
    o[0] = (bf16)v.x; o[1] = (bf16)v.y; o[2] = (bf16)v.z; o[3] = (bf16)v.w;
    *(bf16x4*)(dst + i) = o;
}

// ---------------- QKV GEMM: [8192x768] x [2304x768]^T -> scatter q,k,v ----------------
// 128x128x32 tiles, 4 waves, double-buffered LDS: STAGE(next) issued before compute,
// so the __syncthreads vmcnt(0) drain lands after ~16 MFMA + 8 ds_read of cover.
#define BM 128
#define BN 128
#define BK 32

#define STAGE_G(Ab, Wb, Abuf, Bbuf, k0) do {                                  \
    gl_lds16((Ab) + (size_t)srow * KDIM + (k0) + scol,        (Abuf) + wv * 512);        \
    gl_lds16((Ab) + (size_t)(srow + 64) * KDIM + (k0) + scol, (Abuf) + 2048 + wv * 512); \
    gl_lds16((Wb) + (size_t)srow * KDIM + (k0) + scol,        (Bbuf) + wv * 512);        \
    gl_lds16((Wb) + (size_t)(srow + 64) * KDIM + (k0) + scol, (Bbuf) + 2048 + wv * 512); \
} while (0)

__global__ __launch_bounds__(256) void k_gemm_qkv(
    const bf16* __restrict__ A, const bf16* __restrict__ W,
    bf16* __restrict__ qb, bf16* __restrict__ kb, bf16* __restrict__ vb)
{
    __shared__ bf16 As[2][BM * BK];
    __shared__ bf16 Bs[2][BN * BK];
    const int t = threadIdx.x;
    const int lane = t & 63;
    const int wv = t >> 6;
    const int wr = wv >> 1, wc = wv & 1;
    const int lr = lane & 15, lkb = (lane >> 4) * 8;
    const int bm = blockIdx.x, bn = blockIdx.y;

    const bf16* Ab = A + (size_t)bm * BM * KDIM;
    const bf16* Wb = W + (size_t)bn * BN * KDIM;

    const int srow = t >> 2;           // 0..63 (= wv*16 + lane/4); LDS dst is lane-linear
    const int scol = (t & 3) * 8;

    f32x4 acc[4][4] = {};

    STAGE_G(Ab, Wb, As[0], Bs[0], 0);
    __syncthreads();                   // vmcnt(0) drain: buf0 ready

    int cur = 0;
    for (int k0 = 0; k0 < KDIM; k0 += BK) {
        if (k0 + BK < KDIM)
            STAGE_G(Ab, Wb, As[cur ^ 1], Bs[cur ^ 1], k0 + BK);  // async, overlaps below
        bf16x8 af[4], bfr[4];
#pragma unroll
        for (int m = 0; m < 4; ++m)
            af[m] = *(const bf16x8*)&As[cur][(wr * 64 + m * 16 + lr) * BK + lkb];
#pragma unroll
        for (int n = 0; n < 4; ++n)
            bfr[n] = *(const bf16x8*)&Bs[cur][(wc * 64 + n * 16 + lr) * BK + lkb];
#pragma unroll
        for (int m = 0; m < 4; ++m)
#pragma unroll
            for (int n = 0; n < 4; ++n)
                acc[m][n] = __builtin_amdgcn_mfma_f32_16x16x32_bf16(af[m], bfr[n], acc[m][n], 0, 0, 0);
        __syncthreads();               // drains prefetch (covered) + read/write fence
        cur ^= 1;
    }

    const float QSC = 0.18033688011112042f;  // 0.125 * log2(e) folded into q
#pragma unroll
    for (int n = 0; n < 4; ++n) {
        int o = bn * BN + wc * 64 + n * 16 + lr;
        int s = o / 768;
        int rem = o - s * 768;
        int head = rem >> 6;
        int d = o & 63;
        bf16* dst = (s == 0) ? qb : ((s == 1) ? kb : vb);
        float sc = (s == 0) ? QSC : 1.0f;
#pragma unroll
        for (int m = 0; m < 4; ++m) {
            int grow = bm * BM + wr * 64 + m * 16 + (lane >> 4) * 4;
            int bidx = grow >> 10;
            int tok = grow & 1023;
            size_t base = (((size_t)bidx * NHEAD + head) * NTOK + tok) * HDIM + d;
#pragma unroll
            for (int r = 0; r < 4; ++r)
                dst[base + (size_t)r * HDIM] = (bf16)(acc[m][n][r] * sc);
        }
    }
}

// ---------------- Proj GEMM: [8192x768] x [768x768]^T + bias -> fp32 out ----------------
__global__ __launch_bounds__(256) void k_gemm_proj(
    const bf16* __restrict__ A, const bf16* __restrict__ W,
    const float* __restrict__ bias, float* __restrict__ out)
{
    __shared__ bf16 As[2][BM * BK];
    __shared__ bf16 Bs[2][BN * BK];
    const int t = threadIdx.x;
    const int lane = t & 63;
    const int wv = t >> 6;
    const int wr = wv >> 1, wc = wv & 1;
    const int lr = lane & 15, lkb = (lane >> 4) * 8;
    const int bm = blockIdx.x, bn = blockIdx.y;

    const bf16* Ab = A + (size_t)bm * BM * KDIM;
    const bf16* Wb = W + (size_t)bn * BN * KDIM;

    const int srow = t >> 2;
    const int scol = (t & 3) * 8;

    f32x4 acc[4][4] = {};

    STAGE_G(Ab, Wb, As[0], Bs[0], 0);
    __syncthreads();

    int cur = 0;
    for (int k0 = 0; k0 < KDIM; k0 += BK) {
        if (k0 + BK < KDIM)
            STAGE_G(Ab, Wb, As[cur ^ 1], Bs[cur ^ 1], k0 + BK);
        bf16x8 af[4], bfr[4];
#pragma unroll
        for (int m = 0; m < 4; ++m)
            af[m] = *(const bf16x8*)&As[cur][(wr * 64 + m * 16 + lr) * BK + lkb];
#pragma unroll
        for (int n = 0; n < 4; ++n)
            bfr[n] = *(const bf16x8*)&Bs[cur][(wc * 64 + n * 16 + lr) * BK + lkb];
#pragma unroll
        for (int m = 0; m < 4; ++m)
#pragma unroll
            for (int n = 0; n < 4; ++n)
                acc[m][n] = __builtin_amdgcn_mfma_f32_16x16x32_bf16(af[m], bfr[n], acc[m][n], 0, 0, 0);
        __syncthreads();
        cur ^= 1;
    }

#pragma unroll
    for (int n = 0; n < 4; ++n) {
        int col = bn * BN + wc * 64 + n * 16 + lr;
        float bv = bias[col];
#pragma unroll
        for (int m = 0; m < 4; ++m) {
            int grow = bm * BM + wr * 64 + m * 16 + (lane >> 4) * 4;
#pragma unroll
            for (int r = 0; r < 4; ++r)
                out[(size_t)(grow + r) * KDIM + col] = acc[m][n][r] + bv;
        }
    }
}

// ---------------- banded flash attention ----------------
// grid: 1536 blocks XCD-swizzled. 4 waves x 16 q-rows; visible key tiles j in
// {wv-1,wv,wv+1}. K/V LDS double-buffered -> ONE barrier per kh; next kh's K/V
// reg-prefetched (vmcnt never drained in-loop by the barrier path).
__global__ __launch_bounds__(256) void k_attn(
    const bf16* __restrict__ qbuf, const bf16* __restrict__ kbuf,
    const bf16* __restrict__ vbuf, bf16* __restrict__ ob)
{
    const int x = blockIdx.x;
    const int sub = x >> 3;
    const int bh = (x & 7) * 12 + (sub >> 4);   // 12 bh per XCD
    const int qblk = sub & 15;                   // == h_q
    const int head = bh % NHEAD, bidx = bh / NHEAD;
    const bf16* Q  = qbuf + (size_t)bh * NTOK * HDIM;
    const bf16* Kp = kbuf + (size_t)bh * NTOK * HDIM;
    const bf16* Vp = vbuf + (size_t)bh * NTOK * HDIM;

    const int t = threadIdx.x, lane = t & 63, wv = t >> 6;
    const int lr = lane & 15, lg = lane >> 4, lkb = lg * 8;

    __shared__ bf16 Ks[2][64 * 64];   // [key][d], swizzled
    __shared__ bf16 vT[2][64 * 64];   // [d][key], swizzled
    __shared__ bf16 pls[4][16 * 64];  // per-wave P [q][key], swizzled

    // zero own wave's P tile once (invisible key tiles are never written)
    {
        bf16x8 z = {};
        *(bf16x8*)&pls[wv][lane * 16] = z;
        *(bf16x8*)&pls[wv][lane * 16 + 8] = z;
    }

    bf16x8 qf[2];
#pragma unroll
    for (int ks = 0; ks < 2; ++ks)
        qf[ks] = *(const bf16x8*)(Q + (size_t)(qblk * 64 + wv * 16 + lr) * HDIM + ks * 32 + lkb);

    f32x4 acc[4] = {};
    float mrow[4] = {-1e30f, -1e30f, -1e30f, -1e30f};
    float lrow[4] = {0.f, 0.f, 0.f, 0.f};

    const int kh0 = (qblk - 3 < 0) ? 0 : qblk - 3;
    const int kh1 = (qblk + 3 > 15) ? 15 : qblk + 3;

    const int sj = t >> 2;           // staged key 0..63
    const int sd = (t & 3) * 16;     // staged d elt 0,16,32,48

    const bf16* ks0 = Kp + (size_t)(kh0 * 64 + sj) * HDIM + sd;
    const bf16* vs0 = Vp + (size_t)(kh0 * 64 + sj) * HDIM + sd;
    bf16x8 gk0 = *(const bf16x8*)ks0, gk1 = *(const bf16x8*)(ks0 + 8);
    bf16x8 gv0 = *(const bf16x8*)vs0, gv1 = *(const bf16x8*)(vs0 + 8);

    char* pb8 = (char*)pls[wv];
    const int wq0 = wv * 16 + lg * 4;
    int cur = 0;

    for (int kh = kh0; kh <= kh1; ++kh) {
        char* kb8 = (char*)Ks[cur];
        char* vb8 = (char*)vT[cur];
        // stage K (row-major, swizzled) into buf[cur] (nobody reads it: they read cur^1)
        {
            int kbo = sj * 128 + sd * 2;
            *(bf16x8*)(kb8 + SWZ(sj, kbo)) = gk0;
            *(bf16x8*)(kb8 + SWZ(sj, kbo + 16)) = gk1;
        }
#pragma unroll
        for (int ii = 0; ii < 8; ++ii) {
            int d = sd + ii;
            *(bf16*)(vb8 + SWZ(d, (d << 7) + (sj << 1))) = gv0[ii];
        }
#pragma unroll
        for (int ii = 0; ii < 8; ++ii) {
            int d = sd + 8 + ii;
            *(bf16*)(vb8 + SWZ(d, (d << 7) + (sj << 1))) = gv1[ii];
        }
        // prefetch next kh's K/V (in flight across the barrier)
        if (kh < kh1) {
            const bf16* kn = Kp + (size_t)((kh + 1) * 64 + sj) * HDIM + sd;
            const bf16* vn = Vp + (size_t)((kh + 1) * 64 + sj) * HDIM + sd;
            gk0 = *(const bf16x8*)kn; gk1 = *(const bf16x8*)(kn + 8);
            gv0 = *(const bf16x8*)vn; gv1 = *(const bf16x8*)(vn + 8);
        }
        asm volatile("s_waitcnt lgkmcnt(0)" ::: "memory");
        __builtin_amdgcn_s_barrier();

        // ---- QK^T over visible key tiles ----
        f32x4 s[3];
#pragma unroll
        for (int jj = 0; jj < 3; ++jj) {
            int j = wv - 1 + jj;
            if (j >= 0 && j <= 3) {        // wave-uniform
                int key = j * 16 + lr;
                int kbase = key * 128;
                bf16x8 kf0 = *(const bf16x8*)(kb8 + SWZ(key, kbase + lg * 16));
                bf16x8 kf1 = *(const bf16x8*)(kb8 + SWZ(key, kbase + 64 + lg * 16));
                f32x4 sv = {};
                sv = __builtin_amdgcn_mfma_f32_16x16x32_bf16(qf[0], kf0, sv, 0, 0, 0);
                sv = __builtin_amdgcn_mfma_f32_16x16x32_bf16(qf[1], kf1, sv, 0, 0, 0);
#pragma unroll
                for (int r = 0; r < 4; ++r) {
                    int dw = wq0 + r - key;
                    sv[r] = (dw >= -5 && dw <= 5) ? sv[r] : -1e30f;
                }
                s[jj] = sv;
            } else {
                s[jj] = f32x4{-1e30f, -1e30f, -1e30f, -1e30f};
            }
        }

        // ---- online softmax, once per kh ----
        float pm[4], scl[4];
#pragma unroll
        for (int r = 0; r < 4; ++r) pm[r] = fmaxf(fmaxf(s[0][r], s[1][r]), s[2][r]);
#pragma unroll
        for (int off = 1; off < 16; off <<= 1)
#pragma unroll
            for (int r = 0; r < 4; ++r) pm[r] = fmaxf(pm[r], __shfl_xor(pm[r], off));
#pragma unroll
        for (int r = 0; r < 4; ++r) {
            float mn = fmaxf(mrow[r], pm[r]);
            scl[r] = exp2f(mrow[r] - mn);
            mrow[r] = mn;
        }
#pragma unroll
        for (int dt = 0; dt < 4; ++dt)
#pragma unroll
            for (int r = 0; r < 4; ++r) acc[dt][r] *= scl[r];

        // ---- P = exp2(s - m) -> bf16 -> per-wave LDS tile ----
        float psum[4] = {0.f, 0.f, 0.f, 0.f};
#pragma unroll
        for (int jj = 0; jj < 3; ++jj) {
            int j = wv - 1 + jj;
            if (j >= 0 && j <= 3) {
#pragma unroll
                for (int r = 0; r < 4; ++r) {
                    float p = exp2f(s[jj][r] - mrow[r]);
                    psum[r] += p;
                    int row = lg * 4 + r;
                    *(bf16*)(pb8 + SWZ(row, row * 128 + (j * 16 + lr) * 2)) = (bf16)p;
                }
            }
        }
#pragma unroll
        for (int r = 0; r < 4; ++r) lrow[r] = lrow[r] * scl[r] + psum[r];

        // ---- PV: A = P[16x64], B = V^T ----
        bf16x8 pf0 = *(const bf16x8*)(pb8 + SWZ(lr, lr * 128 + lg * 16));
        bf16x8 pf1 = *(const bf16x8*)(pb8 + SWZ(lr, lr * 128 + 64 + lg * 16));
#pragma unroll
        for (int dt = 0; dt < 4; ++dt) {
            int vrow = dt * 16 + lr;
            bf16x8 vf0 = *(const bf16x8*)(vb8 + SWZ(vrow, vrow * 128 + lg * 16));
            bf16x8 vf1 = *(const bf16x8*)(vb8 + SWZ(vrow, vrow * 128 + 64 + lg * 16));
            acc[dt] = __builtin_amdgcn_mfma_f32_16x16x32_bf16(pf0, vf0, acc[dt], 0, 0, 0);
            acc[dt] = __builtin_amdgcn_mfma_f32_16x16x32_bf16(pf1, vf1, acc[dt], 0, 0, 0);
        }
        cur ^= 1;
    } // kh

    // ---- finalize ----
#pragma unroll
    for (int off = 1; off < 16; off <<= 1)
#pragma unroll
        for (int r = 0; r < 4; ++r) lrow[r] += __shfl_xor(lrow[r], off);

#pragma unroll
    for (int r = 0; r < 4; ++r) {
        float inv = 1.0f / lrow[r];
        int tok = qblk * 64 + wv * 16 + lg * 4 + r;
        size_t rowbase = ((size_t)bidx * NTOK + tok) * KDIM + head * HDIM;
#pragma unroll
        for (int dt = 0; dt < 4; ++dt)
            ob[rowbase + dt * 16 + lr] = (bf16)(acc[dt][r] * inv);
    }
}

// ---------------- launcher ----------------
extern "C" void kernel_launch(void* const* d_in, const int* in_sizes, int n_in,
                              void* d_out, int out_size, void* d_ws, size_t ws_size,
                              hipStream_t stream) {
    const float* x      = (const float*)d_in[0];
    const float* w_qkv  = (const float*)d_in[1];
    const float* w_proj = (const float*)d_in[2];
    const float* b_proj = (const float*)d_in[3];
    float* out = (float*)d_out;

    char* ws = (char*)d_ws;
    bf16* xb  = (bf16*)(ws);                  // 8192*768*2   = 12582912
    bf16* wqb = (bf16*)(ws + 12582912);       // 2304*768*2   =  3538944
    bf16* wpb = (bf16*)(ws + 16121856);       // 768*768*2    =  1179648
    bf16* qb  = (bf16*)(ws + 17301504);       // 96*1024*64*2 = 12582912
    bf16* kb  = (bf16*)(ws + 29884416);
    bf16* vb  = (bf16*)(ws + 42467328);
    bf16* aob = (bf16*)(ws + 55050240);       // attn out bf16 [8192][768]

    hipLaunchKernelGGL(k_cvt_all, dim3(8448), dim3(256), 0, stream, x, w_qkv, w_proj, xb, wqb, wpb);
    hipLaunchKernelGGL(k_gemm_qkv, dim3(64, 18), dim3(256), 0, stream, xb, wqb, qb, kb, vb);
    hipLaunchKernelGGL(k_attn,     dim3(1536), dim3(256), 0, stream, qb, kb, vb, aob);
    hipLaunchKernelGGL(k_gemm_proj, dim3(64, 6), dim3(256), 0, stream, aob, wpb, b_proj, out);
}

// Round 4
// 105.594 us; speedup vs baseline: 1.4801x; 1.0425x over previous
//
#include <hip/hip_runtime.h>
#include <hip/hip_bf16.h>
#include <stdint.h>

typedef __bf16 bf16;
typedef __bf16 bf16x8 __attribute__((ext_vector_type(8)));
typedef __bf16 bf16x4 __attribute__((ext_vector_type(4)));
typedef float f32x4 __attribute__((ext_vector_type(4)));

#define KDIM 768
#define NHEAD 12
#define HDIM 64
#define NTOK 1024
#define BATCH 8

// XOR swizzle for row-major [row][128B-row] LDS tiles: 16B chunk -> distinct bank-quad
#define SWZ(row, b) ((b) ^ (((row) & 7) << 4))

__device__ __forceinline__ void gl_lds16(const bf16* g, bf16* l) {
    __builtin_amdgcn_global_load_lds((const __attribute__((address_space(1))) void*)g,
                                     (__attribute__((address_space(3))) void*)l, 16, 0, 0);
}

// ---------------- fp32 -> bf16 convert (all three tensors, one launch) ----------------
__global__ void k_cvt_all(const float* __restrict__ x, const float* __restrict__ wq,
                          const float* __restrict__ wp, bf16* __restrict__ xb,
                          bf16* __restrict__ wqb, bf16* __restrict__ wpb) {
    int b = blockIdx.x;
    const float* src;
    bf16* dst;
    int base;
    if (b < 6144)       { src = x;  dst = xb;  base = b; }
    else if (b < 7872)  { src = wq; dst = wqb; base = b - 6144; }
    else                { src = wp; dst = wpb; base = b - 7872; }
    int i = (base * 256 + threadIdx.x) * 4;
    float4 v = *(const float4*)(src + i);
    bf16x4 o;
    o[0] = (bf16)v.x; o[1] = (bf16)v.y; o[2] = (bf16)v.z; o[3] = (bf16)v.w;
    *(bf16x4*)(dst + i) = o;
}

// ---------------- GEMM tiles: 128x128x32, 4 waves ----------------
// LDS tile layout: 64 rows x 128B; tile-row r, 16B-chunk c (k-chunk of 8 bf16):
//   byte(r,c) = (r>>1)*128 + (((r&1)*64 + c*16) ^ (((r>>1)&7)<<4))
// global_load_lds writes lane-linear, so the per-lane GLOBAL source is pre-permuted
// with the same involution (rule: both-sides-or-neither). Frag reads then hit each
// bank-quad exactly 8x per wave (conflict-free for ds_read_b128).
#define BM 128
#define BN 128
#define BK 32

// depth-2 pipeline: stage tile t+2 while computing t; vmcnt(4) keeps the next
// buffer's 4 loads the only drained ones (T4 counted-vmcnt; never vmcnt(0) in-loop)
#define STAGE_G(Ab, Wb, Abuf, Bbuf, k0) do {                                   \
    gl_lds16((Ab) + (size_t)sr0 * KDIM + (k0) + sc0, (Abuf) + wv * 512);        \
    gl_lds16((Ab) + (size_t)sr1 * KDIM + (k0) + sc1, (Abuf) + 2048 + wv * 512); \
    gl_lds16((Wb) + (size_t)sr0 * KDIM + (k0) + sc0, (Bbuf) + wv * 512);        \
    gl_lds16((Wb) + (size_t)sr1 * KDIM + (k0) + sc1, (Bbuf) + 2048 + wv * 512); \
} while (0)

#define GEMM_PRE()                                                              \
    const int t = threadIdx.x;                                                  \
    const int lane = t & 63;                                                    \
    const int wv = t >> 6;                                                      \
    const int wr = wv >> 1, wc = wv & 1;                                        \
    const int lr = lane & 15, lg = lane >> 4;                                   \
    /* staging source map: chunk q -> (row, k-chunk) after unswizzle */         \
    const int q0 = wv * 64 + lane;                                              \
    const int R0 = q0 >> 3, wp0 = (q0 & 7) ^ (R0 & 7);                          \
    const int sr0 = 2 * R0 + (wp0 >> 2), sc0 = (wp0 & 3) * 8;                   \
    const int q1 = 256 + wv * 64 + lane;                                        \
    const int R1 = q1 >> 3, wp1 = (q1 & 7) ^ (R1 & 7);                          \
    const int sr1 = 2 * R1 + (wp1 >> 2), sc1 = (wp1 & 3) * 8;                   \
    /* frag-read offsets */                                                     \
    const int rhalf = lr >> 1;                                                  \
    const int xorp = (((lr & 1) * 64 + lg * 16) ^ (rhalf << 4));

#define GEMM_LOOP(Ab, Wb)                                                       \
    f32x4 acc[4][4] = {};                                                       \
    STAGE_G(Ab, Wb, As[0], Bs[0], 0);                                           \
    STAGE_G(Ab, Wb, As[1], Bs[1], BK);                                          \
    asm volatile("s_waitcnt vmcnt(4)" ::: "memory");                            \
    __builtin_amdgcn_s_barrier();                                               \
    for (int tt = 0; tt < 24; ++tt) {                                           \
        int p = tt & 1;                                                         \
        const char* Ab8 = (const char*)As[p];                                   \
        const char* Bb8 = (const char*)Bs[p];                                   \
        bf16x8 af[4], bfr[4];                                                   \
        _Pragma("unroll")                                                       \
        for (int m = 0; m < 4; ++m)                                             \
            af[m] = *(const bf16x8*)(Ab8 + (wr * 32 + m * 8 + rhalf) * 128 + xorp); \
        _Pragma("unroll")                                                       \
        for (int n = 0; n < 4; ++n)                                             \
            bfr[n] = *(const bf16x8*)(Bb8 + (wc * 32 + n * 8 + rhalf) * 128 + xorp); \
        asm volatile("s_waitcnt lgkmcnt(0)" ::: "memory");                      \
        __builtin_amdgcn_s_barrier();                                           \
        if (tt < 22) {                                                          \
            STAGE_G(Ab, Wb, As[p], Bs[p], (tt + 2) * BK);                       \
            __builtin_amdgcn_sched_barrier(0);                                  \
        }                                                                       \
        _Pragma("unroll")                                                       \
        for (int m = 0; m < 4; ++m)                                             \
            _Pragma("unroll")                                                   \
            for (int n = 0; n < 4; ++n)                                         \
                acc[m][n] = __builtin_amdgcn_mfma_f32_16x16x32_bf16(af[m], bfr[n], acc[m][n], 0, 0, 0); \
        if (tt < 22)       { asm volatile("s_waitcnt vmcnt(4)" ::: "memory"); } \
        else if (tt == 22) { asm volatile("s_waitcnt vmcnt(0)" ::: "memory"); } \
        __builtin_amdgcn_s_barrier();                                           \
    }

__global__ __launch_bounds__(256) void k_gemm_qkv(
    const bf16* __restrict__ A, const bf16* __restrict__ W,
    bf16* __restrict__ qb, bf16* __restrict__ kb, bf16* __restrict__ vb)
{
    __shared__ bf16 As[2][BM * BK];
    __shared__ bf16 Bs[2][BN * BK];
    GEMM_PRE();
    const int bm = blockIdx.x, bn = blockIdx.y;
    const bf16* Ab = A + (size_t)bm * BM * KDIM;
    const bf16* Wb = W + (size_t)bn * BN * KDIM;
    GEMM_LOOP(Ab, Wb);

    const float QSC = 0.18033688011112042f;  // 0.125 * log2(e) folded into q
#pragma unroll
    for (int n = 0; n < 4; ++n) {
        int o = bn * BN + wc * 64 + n * 16 + lr;
        int s = o / 768;
        int rem = o - s * 768;
        int head = rem >> 6;
        int d = o & 63;
        bf16* dst = (s == 0) ? qb : ((s == 1) ? kb : vb);
        float sc = (s == 0) ? QSC : 1.0f;
#pragma unroll
        for (int m = 0; m < 4; ++m) {
            int grow = bm * BM + wr * 64 + m * 16 + lg * 4;
            int bidx = grow >> 10;
            int tok = grow & 1023;
            size_t base = (((size_t)bidx * NHEAD + head) * NTOK + tok) * HDIM + d;
#pragma unroll
            for (int r = 0; r < 4; ++r)
                dst[base + (size_t)r * HDIM] = (bf16)(acc[m][n][r] * sc);
        }
    }
}

__global__ __launch_bounds__(256) void k_gemm_proj(
    const bf16* __restrict__ A, const bf16* __restrict__ W,
    const float* __restrict__ bias, float* __restrict__ out)
{
    __shared__ bf16 As[2][BM * BK];
    __shared__ bf16 Bs[2][BN * BK];
    GEMM_PRE();
    const int bm = blockIdx.x, bn = blockIdx.y;
    const bf16* Ab = A + (size_t)bm * BM * KDIM;
    const bf16* Wb = W + (size_t)bn * BN * KDIM;
    GEMM_LOOP(Ab, Wb);

#pragma unroll
    for (int n = 0; n < 4; ++n) {
        int col = bn * BN + wc * 64 + n * 16 + lr;
        float bv = bias[col];
#pragma unroll
        for (int m = 0; m < 4; ++m) {
            int grow = bm * BM + wr * 64 + m * 16 + lg * 4;
#pragma unroll
            for (int r = 0; r < 4; ++r)
                out[(size_t)(grow + r) * KDIM + col] = acc[m][n][r] + bv;
        }
    }
}

// ---------------- banded flash attention ----------------
// grid: 1536 blocks XCD-swizzled. 4 waves x 16 q-rows; visible key tiles j in
// {wv-1,wv,wv+1}. K/V LDS double-buffered -> ONE barrier per kh; next kh's K/V
// reg-prefetched (vmcnt never drained in-loop by the barrier path).
__global__ __launch_bounds__(256) void k_attn(
    const bf16* __restrict__ qbuf, const bf16* __restrict__ kbuf,
    const bf16* __restrict__ vbuf, bf16* __restrict__ ob)
{
    const int x = blockIdx.x;
    const int sub = x >> 3;
    const int bh = (x & 7) * 12 + (sub >> 4);   // 12 bh per XCD
    const int qblk = sub & 15;                   // == h_q
    const int head = bh % NHEAD, bidx = bh / NHEAD;
    const bf16* Q  = qbuf + (size_t)bh * NTOK * HDIM;
    const bf16* Kp = kbuf + (size_t)bh * NTOK * HDIM;
    const bf16* Vp = vbuf + (size_t)bh * NTOK * HDIM;

    const int t = threadIdx.x, lane = t & 63, wv = t >> 6;
    const int lr = lane & 15, lg = lane >> 4, lkb = lg * 8;

    __shared__ bf16 Ks[2][64 * 64];   // [key][d], swizzled
    __shared__ bf16 vT[2][64 * 64];   // [d][key], swizzled
    __shared__ bf16 pls[4][16 * 64];  // per-wave P [q][key], swizzled

    // zero own wave's P tile once (invisible key tiles are never written)
    {
        bf16x8 z = {};
        *(bf16x8*)&pls[wv][lane * 16] = z;
        *(bf16x8*)&pls[wv][lane * 16 + 8] = z;
    }

    bf16x8 qf[2];
#pragma unroll
    for (int ks = 0; ks < 2; ++ks)
        qf[ks] = *(const bf16x8*)(Q + (size_t)(qblk * 64 + wv * 16 + lr) * HDIM + ks * 32 + lkb);

    f32x4 acc[4] = {};
    float mrow[4] = {-1e30f, -1e30f, -1e30f, -1e30f};
    float lrow[4] = {0.f, 0.f, 0.f, 0.f};

    const int kh0 = (qblk - 3 < 0) ? 0 : qblk - 3;
    const int kh1 = (qblk + 3 > 15) ? 15 : qblk + 3;

    const int sj = t >> 2;           // staged key 0..63
    const int sd = (t & 3) * 16;     // staged d elt 0,16,32,48

    const bf16* ks0 = Kp + (size_t)(kh0 * 64 + sj) * HDIM + sd;
    const bf16* vs0 = Vp + (size_t)(kh0 * 64 + sj) * HDIM + sd;
    bf16x8 gk0 = *(const bf16x8*)ks0, gk1 = *(const bf16x8*)(ks0 + 8);
    bf16x8 gv0 = *(const bf16x8*)vs0, gv1 = *(const bf16x8*)(vs0 + 8);

    char* pb8 = (char*)pls[wv];
    const int wq0 = wv * 16 + lg * 4;
    int cur = 0;

    for (int kh = kh0; kh <= kh1; ++kh) {
        char* kb8 = (char*)Ks[cur];
        char* vb8 = (char*)vT[cur];
        // stage K (row-major, swizzled) into buf[cur] (nobody reads it: they read cur^1)
        {
            int kbo = sj * 128 + sd * 2;
            *(bf16x8*)(kb8 + SWZ(sj, kbo)) = gk0;
            *(bf16x8*)(kb8 + SWZ(sj, kbo + 16)) = gk1;
        }
#pragma unroll
        for (int ii = 0; ii < 8; ++ii) {
            int d = sd + ii;
            *(bf16*)(vb8 + SWZ(d, (d << 7) + (sj << 1))) = gv0[ii];
        }
#pragma unroll
        for (int ii = 0; ii < 8; ++ii) {
            int d = sd + 8 + ii;
            *(bf16*)(vb8 + SWZ(d, (d << 7) + (sj << 1))) = gv1[ii];
        }
        // prefetch next kh's K/V (in flight across the barrier)
        if (kh < kh1) {
            const bf16* kn = Kp + (size_t)((kh + 1) * 64 + sj) * HDIM + sd;
            const bf16* vn = Vp + (size_t)((kh + 1) * 64 + sj) * HDIM + sd;
            gk0 = *(const bf16x8*)kn; gk1 = *(const bf16x8*)(kn + 8);
            gv0 = *(const bf16x8*)vn; gv1 = *(const bf16x8*)(vn + 8);
        }
        asm volatile("s_waitcnt lgkmcnt(0)" ::: "memory");
        __builtin_amdgcn_s_barrier();

        // ---- QK^T over visible key tiles ----
        f32x4 s[3];
#pragma unroll
        for (int jj = 0; jj < 3; ++jj) {
            int j = wv - 1 + jj;
            if (j >= 0 && j <= 3) {        // wave-uniform
                int key = j * 16 + lr;
                int kbase = key * 128;
                bf16x8 kf0 = *(const bf16x8*)(kb8 + SWZ(key, kbase + lg * 16));
                bf16x8 kf1 = *(const bf16x8*)(kb8 + SWZ(key, kbase + 64 + lg * 16));
                f32x4 sv = {};
                sv = __builtin_amdgcn_mfma_f32_16x16x32_bf16(qf[0], kf0, sv, 0, 0, 0);
                sv = __builtin_amdgcn_mfma_f32_16x16x32_bf16(qf[1], kf1, sv, 0, 0, 0);
#pragma unroll
                for (int r = 0; r < 4; ++r) {
                    int dw = wq0 + r - key;
                    sv[r] = (dw >= -5 && dw <= 5) ? sv[r] : -1e30f;
                }
                s[jj] = sv;
            } else {
                s[jj] = f32x4{-1e30f, -1e30f, -1e30f, -1e30f};
            }
        }

        // ---- online softmax, once per kh ----
        float pm[4], scl[4];
#pragma unroll
        for (int r = 0; r < 4; ++r) pm[r] = fmaxf(fmaxf(s[0][r], s[1][r]), s[2][r]);
#pragma unroll
        for (int off = 1; off < 16; off <<= 1)
#pragma unroll
            for (int r = 0; r < 4; ++r) pm[r] = fmaxf(pm[r], __shfl_xor(pm[r], off));
#pragma unroll
        for (int r = 0; r < 4; ++r) {
            float mn = fmaxf(mrow[r], pm[r]);
            scl[r] = exp2f(mrow[r] - mn);
            mrow[r] = mn;
        }
#pragma unroll
        for (int dt = 0; dt < 4; ++dt)
#pragma unroll
            for (int r = 0; r < 4; ++r) acc[dt][r] *= scl[r];

        // ---- P = exp2(s - m) -> bf16 -> per-wave LDS tile ----
        float psum[4] = {0.f, 0.f, 0.f, 0.f};
#pragma unroll
        for (int jj = 0; jj < 3; ++jj) {
            int j = wv - 1 + jj;
            if (j >= 0 && j <= 3) {
#pragma unroll
                for (int r = 0; r < 4; ++r) {
                    float p = exp2f(s[jj][r] - mrow[r]);
                    psum[r] += p;
                    int row = lg * 4 + r;
                    *(bf16*)(pb8 + SWZ(row, row * 128 + (j * 16 + lr) * 2)) = (bf16)p;
                }
            }
        }
#pragma unroll
        for (int r = 0; r < 4; ++r) lrow[r] = lrow[r] * scl[r] + psum[r];

        // ---- PV: A = P[16x64], B = V^T ----
        bf16x8 pf0 = *(const bf16x8*)(pb8 + SWZ(lr, lr * 128 + lg * 16));
        bf16x8 pf1 = *(const bf16x8*)(pb8 + SWZ(lr, lr * 128 + 64 + lg * 16));
#pragma unroll
        for (int dt = 0; dt < 4; ++dt) {
            int vrow = dt * 16 + lr;
            bf16x8 vf0 = *(const bf16x8*)(vb8 + SWZ(vrow, vrow * 128 + lg * 16));
            bf16x8 vf1 = *(const bf16x8*)(vb8 + SWZ(vrow, vrow * 128 + 64 + lg * 16));
            acc[dt] = __builtin_amdgcn_mfma_f32_16x16x32_bf16(pf0, vf0, acc[dt], 0, 0, 0);
            acc[dt] = __builtin_amdgcn_mfma_f32_16x16x32_bf16(pf1, vf1, acc[dt], 0, 0, 0);
        }
        cur ^= 1;
    } // kh

    // ---- finalize ----
#pragma unroll
    for (int off = 1; off < 16; off <<= 1)
#pragma unroll
        for (int r = 0; r < 4; ++r) lrow[r] += __shfl_xor(lrow[r], off);

#pragma unroll
    for (int r = 0; r < 4; ++r) {
        float inv = 1.0f / lrow[r];
        int tok = qblk * 64 + wv * 16 + lg * 4 + r;
        size_t rowbase = ((size_t)bidx * NTOK + tok) * KDIM + head * HDIM;
#pragma unroll
        for (int dt = 0; dt < 4; ++dt)
            ob[rowbase + dt * 16 + lr] = (bf16)(acc[dt][r] * inv);
    }
}

// ---------------- launcher ----------------
extern "C" void kernel_launch(void* const* d_in, const int* in_sizes, int n_in,
                              void* d_out, int out_size, void* d_ws, size_t ws_size,
                              hipStream_t stream) {
    const float* x      = (const float*)d_in[0];
    const float* w_qkv  = (const float*)d_in[1];
    const float* w_proj = (const float*)d_in[2];
    const float* b_proj = (const float*)d_in[3];
    float* out = (float*)d_out;

    char* ws = (char*)d_ws;
    bf16* xb  = (bf16*)(ws);                  // 8192*768*2   = 12582912
    bf16* wqb = (bf16*)(ws + 12582912);       // 2304*768*2   =  3538944
    bf16* wpb = (bf16*)(ws + 16121856);       // 768*768*2    =  1179648
    bf16* qb  = (bf16*)(ws + 17301504);       // 96*1024*64*2 = 12582912
    bf16* kb  = (bf16*)(ws + 29884416);
    bf16* vb  = (bf16*)(ws + 42467328);
    bf16* aob = (bf16*)(ws + 55050240);       // attn out bf16 [8192][768]

    hipLaunchKernelGGL(k_cvt_all, dim3(8448), dim3(256), 0, stream, x, w_qkv, w_proj, xb, wqb, wpb);
    hipLaunchKernelGGL(k_gemm_qkv, dim3(64, 18), dim3(256), 0, stream, xb, wqb, qb, kb, vb);
    hipLaunchKernelGGL(k_attn,     dim3(1536), dim3(256), 0, stream, qb, kb, vb, aob);
    hipLaunchKernelGGL(k_gemm_proj, dim3(64, 6), dim3(256), 0, stream, aob, wpb, b_proj, out);
}